// Round 1
// baseline (1732.558 us; speedup 1.0000x reference)
//
#include <hip/hip_runtime.h>

#define NN 200000
#define CC 64
#define EE 3200000

// ---------------- scatter: one wave (64 lanes) per edge, lane = channel ----
__global__ void __launch_bounds__(256) scatter2_kernel(
    const float* __restrict__ x,
    const int*   __restrict__ src,
    const int*   __restrict__ dst,
    float*       __restrict__ agg1,   // += x[src] at row dst
    float*       __restrict__ agg2)   // += x[dst] at row src
{
    int tid  = blockIdx.x * blockDim.x + threadIdx.x;
    int e    = tid >> 6;
    int lane = tid & 63;
    if (e >= EE) return;
    int s = src[e];
    int t = dst[e];
    float vs = x[(size_t)s * CC + lane];
    float vt = x[(size_t)t * CC + lane];
    atomicAdd(&agg1[(size_t)t * CC + lane], vs);
    atomicAdd(&agg2[(size_t)s * CC + lane], vt);
}

__global__ void __launch_bounds__(256) scatter1_kernel(
    const float* __restrict__ x,
    const int*   __restrict__ src,
    const int*   __restrict__ dst,
    float*       __restrict__ agg)
{
    int tid  = blockIdx.x * blockDim.x + threadIdx.x;
    int e    = tid >> 6;
    int lane = tid & 63;
    if (e >= EE) return;
    int s = src[e];
    int t = dst[e];
    atomicAdd(&agg[(size_t)t * CC + lane], x[(size_t)s * CC + lane]);
}

// ---------------- fused scale + GEMM(64x64) + relu + add ------------------
// One wave per output row. W^T staged in LDS (lane-consecutive reads ->
// 2-way bank aliasing only, which is free). Row broadcast via __shfl.
__global__ void __launch_bounds__(256) gemm2_kernel(
    const float* __restrict__ x,
    const float* __restrict__ agg1,
    const float* __restrict__ agg2,
    const float* __restrict__ norm,
    const float* __restrict__ norm_t,
    const float* __restrict__ Wo,
    const float* __restrict__ Wb,
    float*       __restrict__ out)
{
    __shared__ float WoT[CC * CC];
    __shared__ float WbT[CC * CC];
    for (int idx = threadIdx.x; idx < CC * CC; idx += blockDim.x) {
        int j = idx >> 6, c = idx & 63;
        WoT[c * CC + j] = Wo[idx];   // W[j][c] -> WT[c][j]
        WbT[c * CC + j] = Wb[idx];
    }
    __syncthreads();

    const int wave       = threadIdx.x >> 6;
    const int lane       = threadIdx.x & 63;
    const int wavesTotal = (gridDim.x * blockDim.x) >> 6;

    for (int i = blockIdx.x * (blockDim.x >> 6) + wave; i < NN; i += wavesTotal) {
        size_t base = (size_t)i * CC + lane;
        float y1 = norm[i]   * (x[base] + agg1[base]);
        float y2 = norm_t[i] * (x[base] + agg2[base]);
        float acc1 = 0.f, acc2 = 0.f;
        #pragma unroll
        for (int c = 0; c < CC; ++c) {
            acc1 = fmaf(__shfl(y1, c, 64), WoT[c * CC + lane], acc1);
            acc2 = fmaf(__shfl(y2, c, 64), WbT[c * CC + lane], acc2);
        }
        out[base] = fmaxf(acc1, 0.f) + fmaxf(acc2, 0.f);
    }
}

template <int ADD>
__global__ void __launch_bounds__(256) gemm1_kernel(
    const float* __restrict__ x,
    const float* __restrict__ agg,
    const float* __restrict__ norm,
    const float* __restrict__ W,
    float*       __restrict__ out)
{
    __shared__ float WT[CC * CC];
    for (int idx = threadIdx.x; idx < CC * CC; idx += blockDim.x) {
        int j = idx >> 6, c = idx & 63;
        WT[c * CC + j] = W[idx];
    }
    __syncthreads();

    const int wave       = threadIdx.x >> 6;
    const int lane       = threadIdx.x & 63;
    const int wavesTotal = (gridDim.x * blockDim.x) >> 6;

    for (int i = blockIdx.x * (blockDim.x >> 6) + wave; i < NN; i += wavesTotal) {
        size_t base = (size_t)i * CC + lane;
        float y = norm[i] * (x[base] + agg[base]);
        float acc = 0.f;
        #pragma unroll
        for (int c = 0; c < CC; ++c) {
            acc = fmaf(__shfl(y, c, 64), WT[c * CC + lane], acc);
        }
        float r = fmaxf(acc, 0.f);
        if (ADD) out[base] += r; else out[base] = r;
    }
}

extern "C" void kernel_launch(void* const* d_in, const int* in_sizes, int n_in,
                              void* d_out, int out_size, void* d_ws, size_t ws_size,
                              hipStream_t stream) {
    const float* x      = (const float*)d_in[0];
    const int*   src    = (const int*)  d_in[1];
    const int*   dst    = (const int*)  d_in[2];
    const float* norm   = (const float*)d_in[3];
    const float* norm_t = (const float*)d_in[4];
    const float* W_out  = (const float*)d_in[5];
    const float* W_back = (const float*)d_in[6];
    float*       out    = (float*)d_out;

    const size_t aggElems = (size_t)NN * CC;
    const size_t aggBytes = aggElems * sizeof(float);

    const int scatterBlocks = (EE * 64) / 256;   // one wave per edge
    const int gemmBlocks    = 4096;

    if (ws_size >= 2 * aggBytes) {
        float* agg1 = (float*)d_ws;
        float* agg2 = agg1 + aggElems;
        hipMemsetAsync(d_ws, 0, 2 * aggBytes, stream);
        scatter2_kernel<<<scatterBlocks, 256, 0, stream>>>(x, src, dst, agg1, agg2);
        gemm2_kernel<<<gemmBlocks, 256, 0, stream>>>(x, agg1, agg2, norm, norm_t,
                                                     W_out, W_back, out);
    } else {
        float* agg = (float*)d_ws;
        hipMemsetAsync(d_ws, 0, aggBytes, stream);
        scatter1_kernel<<<scatterBlocks, 256, 0, stream>>>(x, src, dst, agg);
        gemm1_kernel<0><<<gemmBlocks, 256, 0, stream>>>(x, agg, norm, W_out, out);
        hipMemsetAsync(d_ws, 0, aggBytes, stream);
        scatter1_kernel<<<scatterBlocks, 256, 0, stream>>>(x, dst, src, agg);
        gemm1_kernel<1><<<gemmBlocks, 256, 0, stream>>>(x, agg, norm_t, W_back, out);
    }
}

// Round 2
// 1698.307 us; speedup vs baseline: 1.0202x; 1.0202x over previous
//
#include <hip/hip_runtime.h>

#define NN 200000
#define CC 64
#define EE 3200000

#define SCAN_BLK 256
#define SCAN_ITEMS 4
#define SCAN_CHUNK (SCAN_BLK * SCAN_ITEMS)              // 1024
#define NB ((NN + SCAN_CHUNK - 1) / SCAN_CHUNK)         // 196
static_assert(NB <= SCAN_BLK, "partials must fit one block");

// ---------------- CSR build: degree count ---------------------------------
__global__ void __launch_bounds__(256) count_kernel(
    const int* __restrict__ src, const int* __restrict__ dst,
    int* __restrict__ deg1, int* __restrict__ deg2)
{
    int e = blockIdx.x * blockDim.x + threadIdx.x;
    if (e >= EE) return;
    atomicAdd(&deg1[dst[e]], 1);   // dir1: rows keyed by target
    atomicAdd(&deg2[src[e]], 1);   // dir2: rows keyed by source
}

// ---------------- CSR build: per-block reduce (partials) ------------------
__global__ void __launch_bounds__(SCAN_BLK) reduce_kernel(
    const int* __restrict__ deg1, const int* __restrict__ deg2,
    int* __restrict__ p1, int* __restrict__ p2)
{
    __shared__ int s1[SCAN_BLK], s2[SCAN_BLK];
    int t = threadIdx.x, b = blockIdx.x;
    int base = b * SCAN_CHUNK + t * SCAN_ITEMS;
    int a = 0, c = 0;
    #pragma unroll
    for (int k = 0; k < SCAN_ITEMS; ++k) {
        int i = base + k;
        if (i < NN) { a += deg1[i]; c += deg2[i]; }
    }
    s1[t] = a; s2[t] = c; __syncthreads();
    for (int ofs = SCAN_BLK / 2; ofs > 0; ofs >>= 1) {
        if (t < ofs) { s1[t] += s1[t + ofs]; s2[t] += s2[t + ofs]; }
        __syncthreads();
    }
    if (t == 0) { p1[b] = s1[0]; p2[b] = s2[0]; }
}

// ---------------- CSR build: scan partials (single block) -----------------
__global__ void __launch_bounds__(SCAN_BLK) scanp_kernel(
    int* __restrict__ p1, int* __restrict__ p2)
{
    __shared__ int s[SCAN_BLK];
    int t = threadIdx.x;

    int v = (t < NB) ? p1[t] : 0;
    s[t] = v; __syncthreads();
    for (int ofs = 1; ofs < SCAN_BLK; ofs <<= 1) {
        int nv = (t >= ofs) ? s[t - ofs] : 0; __syncthreads();
        s[t] += nv; __syncthreads();
    }
    if (t < NB) p1[t] = s[t] - v;          // exclusive
    __syncthreads();

    v = (t < NB) ? p2[t] : 0;
    s[t] = v; __syncthreads();
    for (int ofs = 1; ofs < SCAN_BLK; ofs <<= 1) {
        int nv = (t >= ofs) ? s[t - ofs] : 0; __syncthreads();
        s[t] += nv; __syncthreads();
    }
    if (t < NB) p2[t] = s[t] - v;
}

// ---------------- CSR build: per-element offsets --------------------------
__global__ void __launch_bounds__(SCAN_BLK) offsets_kernel(
    const int* __restrict__ deg1, const int* __restrict__ deg2,
    const int* __restrict__ p1, const int* __restrict__ p2,
    int* __restrict__ off1, int* __restrict__ off2,
    int* __restrict__ cur1, int* __restrict__ cur2)
{
    __shared__ int s[SCAN_BLK];
    int t = threadIdx.x, b = blockIdx.x;
    int base = b * SCAN_CHUNK + t * SCAN_ITEMS;

    // --- dir1 ---
    {
        int d[SCAN_ITEMS]; int sum = 0;
        #pragma unroll
        for (int k = 0; k < SCAN_ITEMS; ++k) {
            int i = base + k;
            d[k] = (i < NN) ? deg1[i] : 0;
            sum += d[k];
        }
        s[t] = sum; __syncthreads();
        for (int ofs = 1; ofs < SCAN_BLK; ofs <<= 1) {
            int nv = (t >= ofs) ? s[t - ofs] : 0; __syncthreads();
            s[t] += nv; __syncthreads();
        }
        int run = s[t] - sum + p1[b];       // exclusive prefix + block offset
        #pragma unroll
        for (int k = 0; k < SCAN_ITEMS; ++k) {
            int i = base + k;
            if (i < NN) { off1[i] = run; cur1[i] = run; }
            run += d[k];
        }
    }
    __syncthreads();
    // --- dir2 ---
    {
        int d[SCAN_ITEMS]; int sum = 0;
        #pragma unroll
        for (int k = 0; k < SCAN_ITEMS; ++k) {
            int i = base + k;
            d[k] = (i < NN) ? deg2[i] : 0;
            sum += d[k];
        }
        s[t] = sum; __syncthreads();
        for (int ofs = 1; ofs < SCAN_BLK; ofs <<= 1) {
            int nv = (t >= ofs) ? s[t - ofs] : 0; __syncthreads();
            s[t] += nv; __syncthreads();
        }
        int run = s[t] - sum + p2[b];
        #pragma unroll
        for (int k = 0; k < SCAN_ITEMS; ++k) {
            int i = base + k;
            if (i < NN) { off2[i] = run; cur2[i] = run; }
            run += d[k];
        }
    }
}

// ---------------- CSR build: fill adjacency -------------------------------
__global__ void __launch_bounds__(256) fill_kernel(
    const int* __restrict__ src, const int* __restrict__ dst,
    int* __restrict__ cur1, int* __restrict__ cur2,
    int* __restrict__ adj1, int* __restrict__ adj2)
{
    int e = blockIdx.x * blockDim.x + threadIdx.x;
    if (e >= EE) return;
    int s = src[e], t = dst[e];
    int p = atomicAdd(&cur1[t], 1); adj1[p] = s;   // in-neighbors of t
    int q = atomicAdd(&cur2[s], 1); adj2[q] = t;   // out-neighbors of s
}

// ---------------- fused gather + scale + GEMM + relu + add ----------------
__global__ void __launch_bounds__(256) gather_gemm_kernel(
    const float* __restrict__ x,
    const int* __restrict__ off1, const int* __restrict__ deg1, const int* __restrict__ adj1,
    const int* __restrict__ off2, const int* __restrict__ deg2, const int* __restrict__ adj2,
    const float* __restrict__ norm, const float* __restrict__ norm_t,
    const float* __restrict__ Wo, const float* __restrict__ Wb,
    float* __restrict__ out)
{
    __shared__ float WoT[CC * CC];
    __shared__ float WbT[CC * CC];
    for (int idx = threadIdx.x; idx < CC * CC; idx += blockDim.x) {
        int j = idx >> 6, c = idx & 63;
        WoT[c * CC + j] = Wo[idx];
        WbT[c * CC + j] = Wb[idx];
    }
    __syncthreads();

    const int wave       = threadIdx.x >> 6;
    const int lane       = threadIdx.x & 63;
    const int wavesTotal = (gridDim.x * blockDim.x) >> 6;

    for (int i = blockIdx.x * (blockDim.x >> 6) + wave; i < NN; i += wavesTotal) {
        size_t base = (size_t)i * CC + lane;
        float xv = x[base];
        float a1 = xv, a2 = xv;

        // gather dir1: sum_{e: dst=i} x[src]
        {
            int st = off1[i], d = deg1[i];
            for (int b0 = 0; b0 < d; b0 += 64) {
                int cnt  = min(64, d - b0);
                int midx = (lane < cnt) ? adj1[st + b0 + lane] : 0;
                int k = 0;
                for (; k + 3 < cnt; k += 4) {
                    int n0 = __shfl(midx, k, 64),     n1 = __shfl(midx, k + 1, 64);
                    int n2 = __shfl(midx, k + 2, 64), n3 = __shfl(midx, k + 3, 64);
                    float v0 = x[(size_t)n0 * CC + lane];
                    float v1 = x[(size_t)n1 * CC + lane];
                    float v2 = x[(size_t)n2 * CC + lane];
                    float v3 = x[(size_t)n3 * CC + lane];
                    a1 += (v0 + v1) + (v2 + v3);
                }
                for (; k < cnt; ++k) {
                    int nb = __shfl(midx, k, 64);
                    a1 += x[(size_t)nb * CC + lane];
                }
            }
        }
        // gather dir2: sum_{e: src=i} x[dst]
        {
            int st = off2[i], d = deg2[i];
            for (int b0 = 0; b0 < d; b0 += 64) {
                int cnt  = min(64, d - b0);
                int midx = (lane < cnt) ? adj2[st + b0 + lane] : 0;
                int k = 0;
                for (; k + 3 < cnt; k += 4) {
                    int n0 = __shfl(midx, k, 64),     n1 = __shfl(midx, k + 1, 64);
                    int n2 = __shfl(midx, k + 2, 64), n3 = __shfl(midx, k + 3, 64);
                    float v0 = x[(size_t)n0 * CC + lane];
                    float v1 = x[(size_t)n1 * CC + lane];
                    float v2 = x[(size_t)n2 * CC + lane];
                    float v3 = x[(size_t)n3 * CC + lane];
                    a2 += (v0 + v1) + (v2 + v3);
                }
                for (; k < cnt; ++k) {
                    int nb = __shfl(midx, k, 64);
                    a2 += x[(size_t)nb * CC + lane];
                }
            }
        }

        float y1 = norm[i]   * a1;
        float y2 = norm_t[i] * a2;
        float acc1 = 0.f, acc2 = 0.f;
        #pragma unroll
        for (int c = 0; c < CC; ++c) {
            acc1 = fmaf(__shfl(y1, c, 64), WoT[c * CC + lane], acc1);
            acc2 = fmaf(__shfl(y2, c, 64), WbT[c * CC + lane], acc2);
        }
        out[base] = fmaxf(acc1, 0.f) + fmaxf(acc2, 0.f);
    }
}

// ---------------- fallback (round-1 atomic path) --------------------------
__global__ void __launch_bounds__(256) scatter2_kernel(
    const float* __restrict__ x, const int* __restrict__ src, const int* __restrict__ dst,
    float* __restrict__ agg1, float* __restrict__ agg2)
{
    int tid = blockIdx.x * blockDim.x + threadIdx.x;
    int e = tid >> 6, lane = tid & 63;
    if (e >= EE) return;
    int s = src[e], t = dst[e];
    atomicAdd(&agg1[(size_t)t * CC + lane], x[(size_t)s * CC + lane]);
    atomicAdd(&agg2[(size_t)s * CC + lane], x[(size_t)t * CC + lane]);
}

__global__ void __launch_bounds__(256) gemm2_kernel(
    const float* __restrict__ x, const float* __restrict__ agg1, const float* __restrict__ agg2,
    const float* __restrict__ norm, const float* __restrict__ norm_t,
    const float* __restrict__ Wo, const float* __restrict__ Wb, float* __restrict__ out)
{
    __shared__ float WoT[CC * CC];
    __shared__ float WbT[CC * CC];
    for (int idx = threadIdx.x; idx < CC * CC; idx += blockDim.x) {
        int j = idx >> 6, c = idx & 63;
        WoT[c * CC + j] = Wo[idx];
        WbT[c * CC + j] = Wb[idx];
    }
    __syncthreads();
    const int wave = threadIdx.x >> 6, lane = threadIdx.x & 63;
    const int wavesTotal = (gridDim.x * blockDim.x) >> 6;
    for (int i = blockIdx.x * (blockDim.x >> 6) + wave; i < NN; i += wavesTotal) {
        size_t base = (size_t)i * CC + lane;
        float y1 = norm[i]   * (x[base] + agg1[base]);
        float y2 = norm_t[i] * (x[base] + agg2[base]);
        float acc1 = 0.f, acc2 = 0.f;
        #pragma unroll
        for (int c = 0; c < CC; ++c) {
            acc1 = fmaf(__shfl(y1, c, 64), WoT[c * CC + lane], acc1);
            acc2 = fmaf(__shfl(y2, c, 64), WbT[c * CC + lane], acc2);
        }
        out[base] = fmaxf(acc1, 0.f) + fmaxf(acc2, 0.f);
    }
}

extern "C" void kernel_launch(void* const* d_in, const int* in_sizes, int n_in,
                              void* d_out, int out_size, void* d_ws, size_t ws_size,
                              hipStream_t stream) {
    const float* x      = (const float*)d_in[0];
    const int*   src    = (const int*)  d_in[1];
    const int*   dst    = (const int*)  d_in[2];
    const float* norm   = (const float*)d_in[3];
    const float* norm_t = (const float*)d_in[4];
    const float* W_out  = (const float*)d_in[5];
    const float* W_back = (const float*)d_in[6];
    float*       out    = (float*)d_out;

    // workspace layout (ints)
    const size_t csrInts = (size_t)6 * NN + 512 + (size_t)2 * EE;
    if (ws_size >= csrInts * sizeof(int)) {
        int* deg1 = (int*)d_ws;
        int* deg2 = deg1 + NN;
        int* off1 = deg2 + NN;
        int* off2 = off1 + NN;
        int* cur1 = off2 + NN;
        int* cur2 = cur1 + NN;
        int* p1   = cur2 + NN;
        int* p2   = p1 + 256;
        int* adj1 = p2 + 256;
        int* adj2 = adj1 + EE;

        hipMemsetAsync(deg1, 0, 2 * NN * sizeof(int), stream);
        count_kernel<<<(EE + 255) / 256, 256, 0, stream>>>(src, dst, deg1, deg2);
        reduce_kernel<<<NB, SCAN_BLK, 0, stream>>>(deg1, deg2, p1, p2);
        scanp_kernel<<<1, SCAN_BLK, 0, stream>>>(p1, p2);
        offsets_kernel<<<NB, SCAN_BLK, 0, stream>>>(deg1, deg2, p1, p2,
                                                    off1, off2, cur1, cur2);
        fill_kernel<<<(EE + 255) / 256, 256, 0, stream>>>(src, dst, cur1, cur2, adj1, adj2);
        gather_gemm_kernel<<<2048, 256, 0, stream>>>(x, off1, deg1, adj1,
                                                     off2, deg2, adj2,
                                                     norm, norm_t, W_out, W_back, out);
    } else {
        const size_t aggElems = (size_t)NN * CC;
        float* agg1 = (float*)d_ws;
        float* agg2 = agg1 + aggElems;
        hipMemsetAsync(d_ws, 0, 2 * aggElems * sizeof(float), stream);
        scatter2_kernel<<<(EE * 64) / 256, 256, 0, stream>>>(x, src, dst, agg1, agg2);
        gemm2_kernel<<<4096, 256, 0, stream>>>(x, agg1, agg2, norm, norm_t,
                                               W_out, W_back, out);
    }
}

// Round 3
// 1523.295 us; speedup vs baseline: 1.1374x; 1.1149x over previous
//
#include <hip/hip_runtime.h>

#define NN 200000
#define CC 64
#define EE 3200000

#define SCAN_BLK 256
#define SCAN_ITEMS 4
#define SCAN_CHUNK (SCAN_BLK * SCAN_ITEMS)              // 1024
#define NB ((NN + SCAN_CHUNK - 1) / SCAN_CHUNK)         // 196
static_assert(NB <= SCAN_BLK, "partials must fit one block");

// ---------------- x -> bf16 rows (RNE) ------------------------------------
__device__ __forceinline__ unsigned int bf16rne(float f) {
    unsigned int u = __float_as_uint(f);
    return (u + 0x7fffu + ((u >> 16) & 1u)) >> 16;
}

__global__ void __launch_bounds__(256) tobf16_kernel(
    const float* __restrict__ x, unsigned short* __restrict__ xh)
{
    int t = blockIdx.x * blockDim.x + threadIdx.x;
    if (t >= NN * CC / 8) return;
    const float4* x4 = (const float4*)x;
    float4 f0 = x4[2 * t], f1 = x4[2 * t + 1];
    int4 o;
    o.x = (int)(bf16rne(f0.x) | (bf16rne(f0.y) << 16));
    o.y = (int)(bf16rne(f0.z) | (bf16rne(f0.w) << 16));
    o.z = (int)(bf16rne(f1.x) | (bf16rne(f1.y) << 16));
    o.w = (int)(bf16rne(f1.z) | (bf16rne(f1.w) << 16));
    ((int4*)xh)[t] = o;
}

// ---------------- CSR build ------------------------------------------------
__global__ void __launch_bounds__(256) count_kernel(
    const int* __restrict__ src, const int* __restrict__ dst,
    int* __restrict__ deg1, int* __restrict__ deg2)
{
    int e = blockIdx.x * blockDim.x + threadIdx.x;
    if (e >= EE) return;
    atomicAdd(&deg1[dst[e]], 1);
    atomicAdd(&deg2[src[e]], 1);
}

__global__ void __launch_bounds__(SCAN_BLK) reduce_kernel(
    const int* __restrict__ deg1, const int* __restrict__ deg2,
    int* __restrict__ p1, int* __restrict__ p2)
{
    __shared__ int s1[SCAN_BLK], s2[SCAN_BLK];
    int t = threadIdx.x, b = blockIdx.x;
    int base = b * SCAN_CHUNK + t * SCAN_ITEMS;
    int a = 0, c = 0;
    #pragma unroll
    for (int k = 0; k < SCAN_ITEMS; ++k) {
        int i = base + k;
        if (i < NN) { a += deg1[i]; c += deg2[i]; }
    }
    s1[t] = a; s2[t] = c; __syncthreads();
    for (int ofs = SCAN_BLK / 2; ofs > 0; ofs >>= 1) {
        if (t < ofs) { s1[t] += s1[t + ofs]; s2[t] += s2[t + ofs]; }
        __syncthreads();
    }
    if (t == 0) { p1[b] = s1[0]; p2[b] = s2[0]; }
}

__global__ void __launch_bounds__(SCAN_BLK) scanp_kernel(
    int* __restrict__ p1, int* __restrict__ p2)
{
    __shared__ int s[SCAN_BLK];
    int t = threadIdx.x;

    int v = (t < NB) ? p1[t] : 0;
    s[t] = v; __syncthreads();
    for (int ofs = 1; ofs < SCAN_BLK; ofs <<= 1) {
        int nv = (t >= ofs) ? s[t - ofs] : 0; __syncthreads();
        s[t] += nv; __syncthreads();
    }
    if (t < NB) p1[t] = s[t] - v;
    __syncthreads();

    v = (t < NB) ? p2[t] : 0;
    s[t] = v; __syncthreads();
    for (int ofs = 1; ofs < SCAN_BLK; ofs <<= 1) {
        int nv = (t >= ofs) ? s[t - ofs] : 0; __syncthreads();
        s[t] += nv; __syncthreads();
    }
    if (t < NB) p2[t] = s[t] - v;
}

__global__ void __launch_bounds__(SCAN_BLK) offsets_kernel(
    const int* __restrict__ deg1, const int* __restrict__ deg2,
    const int* __restrict__ p1, const int* __restrict__ p2,
    int* __restrict__ off1, int* __restrict__ off2,
    int* __restrict__ cur1, int* __restrict__ cur2)
{
    __shared__ int s[SCAN_BLK];
    int t = threadIdx.x, b = blockIdx.x;
    int base = b * SCAN_CHUNK + t * SCAN_ITEMS;

    {
        int d[SCAN_ITEMS]; int sum = 0;
        #pragma unroll
        for (int k = 0; k < SCAN_ITEMS; ++k) {
            int i = base + k;
            d[k] = (i < NN) ? deg1[i] : 0;
            sum += d[k];
        }
        s[t] = sum; __syncthreads();
        for (int ofs = 1; ofs < SCAN_BLK; ofs <<= 1) {
            int nv = (t >= ofs) ? s[t - ofs] : 0; __syncthreads();
            s[t] += nv; __syncthreads();
        }
        int run = s[t] - sum + p1[b];
        #pragma unroll
        for (int k = 0; k < SCAN_ITEMS; ++k) {
            int i = base + k;
            if (i < NN) { off1[i] = run; cur1[i] = run; }
            run += d[k];
        }
    }
    __syncthreads();
    {
        int d[SCAN_ITEMS]; int sum = 0;
        #pragma unroll
        for (int k = 0; k < SCAN_ITEMS; ++k) {
            int i = base + k;
            d[k] = (i < NN) ? deg2[i] : 0;
            sum += d[k];
        }
        s[t] = sum; __syncthreads();
        for (int ofs = 1; ofs < SCAN_BLK; ofs <<= 1) {
            int nv = (t >= ofs) ? s[t - ofs] : 0; __syncthreads();
            s[t] += nv; __syncthreads();
        }
        int run = s[t] - sum + p2[b];
        #pragma unroll
        for (int k = 0; k < SCAN_ITEMS; ++k) {
            int i = base + k;
            if (i < NN) { off2[i] = run; cur2[i] = run; }
            run += d[k];
        }
    }
}

__global__ void __launch_bounds__(256) fill_kernel(
    const int* __restrict__ src, const int* __restrict__ dst,
    int* __restrict__ cur1, int* __restrict__ cur2,
    int* __restrict__ adj1, int* __restrict__ adj2)
{
    int e = blockIdx.x * blockDim.x + threadIdx.x;
    if (e >= EE) return;
    int s = src[e], t = dst[e];
    int p = atomicAdd(&cur1[t], 1); adj1[p] = s;
    int q = atomicAdd(&cur2[s], 1); adj2[q] = t;
}

// ---------------- fused bf16-gather + scale + GEMM + relu + add -----------
// Wave layout: g = lane>>3 (neighbor group, 8 rows in parallel),
//              l = lane&7  (channel quad-pair: 8 bf16 channels = one int4).
__device__ __forceinline__ void acc_bf8(const int4 u, float a[8]) {
    unsigned int w;
    w = (unsigned int)u.x; a[0] += __uint_as_float(w << 16); a[1] += __uint_as_float(w & 0xffff0000u);
    w = (unsigned int)u.y; a[2] += __uint_as_float(w << 16); a[3] += __uint_as_float(w & 0xffff0000u);
    w = (unsigned int)u.z; a[4] += __uint_as_float(w << 16); a[5] += __uint_as_float(w & 0xffff0000u);
    w = (unsigned int)u.w; a[6] += __uint_as_float(w << 16); a[7] += __uint_as_float(w & 0xffff0000u);
}

__global__ void __launch_bounds__(256) gather_gemm_bf16_kernel(
    const float* __restrict__ x,
    const unsigned short* __restrict__ xh,
    const int* __restrict__ off1, const int* __restrict__ deg1, const int* __restrict__ adj1,
    const int* __restrict__ off2, const int* __restrict__ deg2, const int* __restrict__ adj2,
    const float* __restrict__ norm, const float* __restrict__ norm_t,
    const float* __restrict__ Wo, const float* __restrict__ Wb,
    float* __restrict__ out)
{
    __shared__ float WoT[CC * CC];
    __shared__ float WbT[CC * CC];
    for (int idx = threadIdx.x; idx < CC * CC; idx += blockDim.x) {
        int j = idx >> 6, c = idx & 63;
        WoT[c * CC + j] = Wo[idx];
        WbT[c * CC + j] = Wb[idx];
    }
    __syncthreads();

    const int wave       = threadIdx.x >> 6;
    const int lane       = threadIdx.x & 63;
    const int g          = lane >> 3;
    const int l          = lane & 7;
    const int wavesTotal = (gridDim.x * blockDim.x) >> 6;
    const int4* xh4      = (const int4*)xh;   // 8 int4 per row

    for (int i = blockIdx.x * (blockDim.x >> 6) + wave; i < NN; i += wavesTotal) {
        float a1[8], a2[8];
        #pragma unroll
        for (int t = 0; t < 8; ++t) { a1[t] = 0.f; a2[t] = 0.f; }

        int d1 = deg1[i], st1 = off1[i];
        int d2 = deg2[i], st2 = off2[i];
        int dmax = max(d1, d2);

        for (int b0 = 0; b0 < dmax; b0 += 64) {
            int c1 = min(d1 - b0, 64);
            int c2 = min(d2 - b0, 64);
            int i1 = (lane < c1) ? adj1[st1 + b0 + lane] : 0;
            int i2 = (lane < c2) ? adj2[st2 + b0 + lane] : 0;
            int kmax = max(c1, c2);
            #pragma unroll 2
            for (int k = 0; k < kmax; k += 8) {
                int j  = k + g;
                int n1 = __shfl(i1, j, 64);
                int n2 = __shfl(i2, j, 64);
                if (j < c1) { int4 u = xh4[(size_t)n1 * 8 + l]; acc_bf8(u, a1); }
                if (j < c2) { int4 u = xh4[(size_t)n2 * 8 + l]; acc_bf8(u, a2); }
            }
        }

        // reduce across the 8 neighbor-groups (lane bits 3,4,5)
        #pragma unroll
        for (int t = 0; t < 8; ++t) {
            a1[t] += __shfl_xor(a1[t], 8, 64);
            a1[t] += __shfl_xor(a1[t], 16, 64);
            a1[t] += __shfl_xor(a1[t], 32, 64);
            a2[t] += __shfl_xor(a2[t], 8, 64);
            a2[t] += __shfl_xor(a2[t], 16, 64);
            a2[t] += __shfl_xor(a2[t], 32, 64);
        }

        // self row (fp32, exact), channels [8l, 8l+8)
        {
            const float4* x4 = (const float4*)x;
            float4 s0 = x4[(size_t)i * 16 + 2 * l];
            float4 s1 = x4[(size_t)i * 16 + 2 * l + 1];
            a1[0] += s0.x; a1[1] += s0.y; a1[2] += s0.z; a1[3] += s0.w;
            a1[4] += s1.x; a1[5] += s1.y; a1[6] += s1.z; a1[7] += s1.w;
            a2[0] += s0.x; a2[1] += s0.y; a2[2] += s0.z; a2[3] += s0.w;
            a2[4] += s1.x; a2[5] += s1.y; a2[6] += s1.z; a2[7] += s1.w;
        }

        float nrm  = norm[i];
        float nrmt = norm_t[i];
        #pragma unroll
        for (int t = 0; t < 8; ++t) { a1[t] *= nrm; a2[t] *= nrmt; }

        float acc1 = 0.f, acc2 = 0.f;
        #pragma unroll
        for (int c = 0; c < CC; ++c) {
            acc1 = fmaf(__shfl(a1[c & 7], c >> 3, 64), WoT[c * CC + lane], acc1);
            acc2 = fmaf(__shfl(a2[c & 7], c >> 3, 64), WbT[c * CC + lane], acc2);
        }
        out[(size_t)i * CC + lane] = fmaxf(acc1, 0.f) + fmaxf(acc2, 0.f);
    }
}

// ---------------- fp32 CSR gather fallback --------------------------------
__global__ void __launch_bounds__(256) gather_gemm_kernel(
    const float* __restrict__ x,
    const int* __restrict__ off1, const int* __restrict__ deg1, const int* __restrict__ adj1,
    const int* __restrict__ off2, const int* __restrict__ deg2, const int* __restrict__ adj2,
    const float* __restrict__ norm, const float* __restrict__ norm_t,
    const float* __restrict__ Wo, const float* __restrict__ Wb,
    float* __restrict__ out)
{
    __shared__ float WoT[CC * CC];
    __shared__ float WbT[CC * CC];
    for (int idx = threadIdx.x; idx < CC * CC; idx += blockDim.x) {
        int j = idx >> 6, c = idx & 63;
        WoT[c * CC + j] = Wo[idx];
        WbT[c * CC + j] = Wb[idx];
    }
    __syncthreads();
    const int wave = threadIdx.x >> 6, lane = threadIdx.x & 63;
    const int wavesTotal = (gridDim.x * blockDim.x) >> 6;
    for (int i = blockIdx.x * (blockDim.x >> 6) + wave; i < NN; i += wavesTotal) {
        size_t base = (size_t)i * CC + lane;
        float xv = x[base];
        float a1 = xv, a2 = xv;
        {
            int st = off1[i], d = deg1[i];
            for (int b0 = 0; b0 < d; b0 += 64) {
                int cnt = min(64, d - b0);
                int midx = (lane < cnt) ? adj1[st + b0 + lane] : 0;
                for (int k = 0; k < cnt; ++k)
                    a1 += x[(size_t)__shfl(midx, k, 64) * CC + lane];
            }
        }
        {
            int st = off2[i], d = deg2[i];
            for (int b0 = 0; b0 < d; b0 += 64) {
                int cnt = min(64, d - b0);
                int midx = (lane < cnt) ? adj2[st + b0 + lane] : 0;
                for (int k = 0; k < cnt; ++k)
                    a2 += x[(size_t)__shfl(midx, k, 64) * CC + lane];
            }
        }
        float y1 = norm[i] * a1, y2 = norm_t[i] * a2;
        float acc1 = 0.f, acc2 = 0.f;
        #pragma unroll
        for (int c = 0; c < CC; ++c) {
            acc1 = fmaf(__shfl(y1, c, 64), WoT[c * CC + lane], acc1);
            acc2 = fmaf(__shfl(y2, c, 64), WbT[c * CC + lane], acc2);
        }
        out[base] = fmaxf(acc1, 0.f) + fmaxf(acc2, 0.f);
    }
}

// ---------------- last-resort atomic path ---------------------------------
__global__ void __launch_bounds__(256) scatter2_kernel(
    const float* __restrict__ x, const int* __restrict__ src, const int* __restrict__ dst,
    float* __restrict__ agg1, float* __restrict__ agg2)
{
    int tid = blockIdx.x * blockDim.x + threadIdx.x;
    int e = tid >> 6, lane = tid & 63;
    if (e >= EE) return;
    int s = src[e], t = dst[e];
    atomicAdd(&agg1[(size_t)t * CC + lane], x[(size_t)s * CC + lane]);
    atomicAdd(&agg2[(size_t)s * CC + lane], x[(size_t)t * CC + lane]);
}

__global__ void __launch_bounds__(256) gemm2_kernel(
    const float* __restrict__ x, const float* __restrict__ agg1, const float* __restrict__ agg2,
    const float* __restrict__ norm, const float* __restrict__ norm_t,
    const float* __restrict__ Wo, const float* __restrict__ Wb, float* __restrict__ out)
{
    __shared__ float WoT[CC * CC];
    __shared__ float WbT[CC * CC];
    for (int idx = threadIdx.x; idx < CC * CC; idx += blockDim.x) {
        int j = idx >> 6, c = idx & 63;
        WoT[c * CC + j] = Wo[idx];
        WbT[c * CC + j] = Wb[idx];
    }
    __syncthreads();
    const int wave = threadIdx.x >> 6, lane = threadIdx.x & 63;
    const int wavesTotal = (gridDim.x * blockDim.x) >> 6;
    for (int i = blockIdx.x * (blockDim.x >> 6) + wave; i < NN; i += wavesTotal) {
        size_t base = (size_t)i * CC + lane;
        float y1 = norm[i]   * (x[base] + agg1[base]);
        float y2 = norm_t[i] * (x[base] + agg2[base]);
        float acc1 = 0.f, acc2 = 0.f;
        #pragma unroll
        for (int c = 0; c < CC; ++c) {
            acc1 = fmaf(__shfl(y1, c, 64), WoT[c * CC + lane], acc1);
            acc2 = fmaf(__shfl(y2, c, 64), WbT[c * CC + lane], acc2);
        }
        out[base] = fmaxf(acc1, 0.f) + fmaxf(acc2, 0.f);
    }
}

extern "C" void kernel_launch(void* const* d_in, const int* in_sizes, int n_in,
                              void* d_out, int out_size, void* d_ws, size_t ws_size,
                              hipStream_t stream) {
    const float* x      = (const float*)d_in[0];
    const int*   src    = (const int*)  d_in[1];
    const int*   dst    = (const int*)  d_in[2];
    const float* norm   = (const float*)d_in[3];
    const float* norm_t = (const float*)d_in[4];
    const float* W_out  = (const float*)d_in[5];
    const float* W_back = (const float*)d_in[6];
    float*       out    = (float*)d_out;

    const size_t xhBytes  = (size_t)NN * CC * 2;                  // 25.6 MB
    const size_t csrInts  = (size_t)6 * NN + 512 + (size_t)2 * EE;
    const size_t fullNeed = xhBytes + csrInts * sizeof(int);

    if (ws_size >= fullNeed) {
        unsigned short* xh = (unsigned short*)d_ws;
        int* deg1 = (int*)((char*)d_ws + xhBytes);
        int* deg2 = deg1 + NN;
        int* off1 = deg2 + NN;
        int* off2 = off1 + NN;
        int* cur1 = off2 + NN;
        int* cur2 = cur1 + NN;
        int* p1   = cur2 + NN;
        int* p2   = p1 + 256;
        int* adj1 = p2 + 256;
        int* adj2 = adj1 + EE;

        hipMemsetAsync(deg1, 0, 2 * NN * sizeof(int), stream);
        tobf16_kernel<<<(NN * CC / 8 + 255) / 256, 256, 0, stream>>>(x, xh);
        count_kernel<<<(EE + 255) / 256, 256, 0, stream>>>(src, dst, deg1, deg2);
        reduce_kernel<<<NB, SCAN_BLK, 0, stream>>>(deg1, deg2, p1, p2);
        scanp_kernel<<<1, SCAN_BLK, 0, stream>>>(p1, p2);
        offsets_kernel<<<NB, SCAN_BLK, 0, stream>>>(deg1, deg2, p1, p2,
                                                    off1, off2, cur1, cur2);
        fill_kernel<<<(EE + 255) / 256, 256, 0, stream>>>(src, dst, cur1, cur2, adj1, adj2);
        gather_gemm_bf16_kernel<<<3072, 256, 0, stream>>>(x, xh,
                                                          off1, deg1, adj1,
                                                          off2, deg2, adj2,
                                                          norm, norm_t, W_out, W_back, out);
    } else if (ws_size >= csrInts * sizeof(int)) {
        int* deg1 = (int*)d_ws;
        int* deg2 = deg1 + NN;
        int* off1 = deg2 + NN;
        int* off2 = off1 + NN;
        int* cur1 = off2 + NN;
        int* cur2 = cur1 + NN;
        int* p1   = cur2 + NN;
        int* p2   = p1 + 256;
        int* adj1 = p2 + 256;
        int* adj2 = adj1 + EE;

        hipMemsetAsync(deg1, 0, 2 * NN * sizeof(int), stream);
        count_kernel<<<(EE + 255) / 256, 256, 0, stream>>>(src, dst, deg1, deg2);
        reduce_kernel<<<NB, SCAN_BLK, 0, stream>>>(deg1, deg2, p1, p2);
        scanp_kernel<<<1, SCAN_BLK, 0, stream>>>(p1, p2);
        offsets_kernel<<<NB, SCAN_BLK, 0, stream>>>(deg1, deg2, p1, p2,
                                                    off1, off2, cur1, cur2);
        fill_kernel<<<(EE + 255) / 256, 256, 0, stream>>>(src, dst, cur1, cur2, adj1, adj2);
        gather_gemm_kernel<<<2048, 256, 0, stream>>>(x, off1, deg1, adj1,
                                                     off2, deg2, adj2,
                                                     norm, norm_t, W_out, W_back, out);
    } else {
        const size_t aggElems = (size_t)NN * CC;
        float* agg1 = (float*)d_ws;
        float* agg2 = agg1 + aggElems;
        hipMemsetAsync(d_ws, 0, 2 * aggElems * sizeof(float), stream);
        scatter2_kernel<<<(EE * 64) / 256, 256, 0, stream>>>(x, src, dst, agg1, agg2);
        gemm2_kernel<<<4096, 256, 0, stream>>>(x, agg1, agg2, norm, norm_t,
                                               W_out, W_back, out);
    }
}